// Round 4
// baseline (28.744 us; speedup 1.0000x reference)
//
#include <hip/hip_runtime.h>

// Inverse 1D wavelet reconstruction, 4 levels, KS=6, PAD=1, fully fused.
// C=64, L0=16384 fixed by setup_inputs().
#define C_CH   64
#define L0     16384
#define B_OUT  4096                   // final-level outputs per block
#define NCHUNK ((L0 * 16) / B_OUT)    // 64 chunks per channel

typedef float f32x4 __attribute__((ext_vector_type(4)));
typedef float f32x2 __attribute__((ext_vector_type(2)));

struct Taps {
    float he0, he1, he2, ho0, ho1, ho2;
    float ge0, ge1, ge2, go0, go1, go2;
};

// One synthesis level: y[2t]   = sum_j xpad[t+j]*he[j] + dpad[t+j]*ge[j]
//                      y[2t+1] = sum_j xpad[t+j]*ho[j] + dpad[t+j]*go[j]
// antireflect pad: xpad[0]=2x0-x1, xpad[L+1]=2x[L-1]-x[L-2].
// xp -> x[xlo] (LDS or global), dp -> full detail row (global, length Lx),
// yp -> y[ylo]. Produces pairs for t in [ylo/2, yhi/2]; ylo % 4 == 0.
// Interior: vectorized 2-t loop (3 aligned float2 d-loads, float4 store).
// Boundary chunks handle <=2 leftover t's + the pad formulas scalar.
template <bool GLOBAL_OUT>
__device__ __forceinline__ void synth_level(
    const float* __restrict__ xp, int xlo, int Lx,
    const float* __restrict__ dp,
    float* __restrict__ yp, int ylo, int yhi,
    const Taps& T, int tid, int nthr)
{
    const int tlo = ylo >> 1, thi = yhi >> 1;
    const int tA = (tlo == 0) ? 1 : tlo;                 // skip pad position
    const int tB = (thi == Lx - 1) ? (thi - 1) : thi;

    // vector pairs (t0, t0+1): t0 even, t0 >= max(tA,2), t0+1 <= tB, t0+3 <= Lx-1
    int tV0 = (tA < 2) ? 2 : tA;
    tV0 = (tV0 + 1) & ~1;
    int tVmax = tB - 1; if (tVmax > Lx - 4) tVmax = Lx - 4;
    const int nvec = (tVmax >= tV0) ? (((tVmax - tV0) >> 1) + 1) : 0;

    for (int i = tid; i < nvec; i += nthr) {
        const int t0 = tV0 + 2 * i;
        // d[t0-2..t0+3] via three aligned float2 loads (use middle 4 values)
        const f32x2 b01 = *reinterpret_cast<const f32x2*>(dp + t0 - 2);
        const f32x2 b23 = *reinterpret_cast<const f32x2*>(dp + t0);
        const f32x2 b45 = *reinterpret_cast<const f32x2*>(dp + t0 + 2);
        const float d0 = b01.y, d1 = b23.x, d2 = b23.y, d3 = b45.x;
        const float a0 = xp[t0 - 1 - xlo];
        const float a1 = xp[t0     - xlo];
        const float a2 = xp[t0 + 1 - xlo];
        const float a3 = xp[t0 + 2 - xlo];
        f32x4 v;
        v.x = a0*T.he0 + a1*T.he1 + a2*T.he2 + d0*T.ge0 + d1*T.ge1 + d2*T.ge2;
        v.y = a0*T.ho0 + a1*T.ho1 + a2*T.ho2 + d0*T.go0 + d1*T.go1 + d2*T.go2;
        v.z = a1*T.he0 + a2*T.he1 + a3*T.he2 + d1*T.ge0 + d2*T.ge1 + d3*T.ge2;
        v.w = a1*T.ho0 + a2*T.ho1 + a3*T.ho2 + d1*T.go0 + d2*T.go1 + d3*T.go2;
        f32x4* dst = reinterpret_cast<f32x4*>(yp + (2 * t0 - ylo));
        if (GLOBAL_OUT) __builtin_nontemporal_store(v, dst);
        else            *dst = v;
    }

    // scalar leftovers (only at boundary chunks, <=2 positions total)
    const int tE0 = tV0 + 2 * nvec;
    for (int t = tA + tid; t < tV0; t += nthr) {
        const float a0 = xp[t-1-xlo], a1 = xp[t-xlo], a2 = xp[t+1-xlo];
        const float d0 = dp[t-1], d1 = dp[t], d2 = dp[t+1];
        const float ve = a0*T.he0 + a1*T.he1 + a2*T.he2 + d0*T.ge0 + d1*T.ge1 + d2*T.ge2;
        const float vo = a0*T.ho0 + a1*T.ho1 + a2*T.ho2 + d0*T.go0 + d1*T.go1 + d2*T.go2;
        *reinterpret_cast<f32x2*>(yp + (2*t - ylo)) = f32x2{ve, vo};
    }
    for (int t = tE0 + tid; t <= tB; t += nthr) {
        const float a0 = xp[t-1-xlo], a1 = xp[t-xlo], a2 = xp[t+1-xlo];
        const float d0 = dp[t-1], d1 = dp[t], d2 = dp[t+1];
        const float ve = a0*T.he0 + a1*T.he1 + a2*T.he2 + d0*T.ge0 + d1*T.ge1 + d2*T.ge2;
        const float vo = a0*T.ho0 + a1*T.ho1 + a2*T.ho2 + d0*T.go0 + d1*T.go1 + d2*T.go2;
        *reinterpret_cast<f32x2*>(yp + (2*t - ylo)) = f32x2{ve, vo};
    }
    if (tid == 0) {
        if (tlo == 0) {  // t=0: xpad[0] = 2x0 - x1
            const float x0 = xp[0 - xlo], x1 = xp[1 - xlo];
            const float dd0 = dp[0], dd1 = dp[1];
            const float a0 = 2.0f*x0 - x1, b0 = 2.0f*dd0 - dd1;
            const float ve = a0*T.he0 + x0*T.he1 + x1*T.he2 + b0*T.ge0 + dd0*T.ge1 + dd1*T.ge2;
            const float vo = a0*T.ho0 + x0*T.ho1 + x1*T.ho2 + b0*T.go0 + dd0*T.go1 + dd1*T.go2;
            *reinterpret_cast<f32x2*>(yp + (0 - ylo)) = f32x2{ve, vo};
        }
        if (thi == Lx - 1) {  // t=Lx-1: xpad[Lx+1] = 2x[L-1] - x[L-2]
            const int t = Lx - 1;
            const float xm = xp[t-1-xlo], xl = xp[t-xlo];
            const float dm = dp[t-1], dl = dp[t];
            const float a2 = 2.0f*xl - xm, b2 = 2.0f*dl - dm;
            const float ve = xm*T.he0 + xl*T.he1 + a2*T.he2 + dm*T.ge0 + dl*T.ge1 + b2*T.ge2;
            const float vo = xm*T.ho0 + xl*T.ho1 + a2*T.ho2 + dm*T.go0 + dl*T.go1 + b2*T.go2;
            *reinterpret_cast<f32x2*>(yp + (2*t - ylo)) = f32x2{ve, vo};
        }
    }
}

__global__ __launch_bounds__(256) void iwt_fused_kernel(
    const float* __restrict__ sig,   // (C, L0)
    const float* __restrict__ d0,    // (C, 8*L0)
    const float* __restrict__ d1,    // (C, 4*L0)
    const float* __restrict__ d2,    // (C, 2*L0)
    const float* __restrict__ d3,    // (C, L0)
    const float* __restrict__ h,     // (6,)
    const float* __restrict__ g,     // (6,)
    float* __restrict__ out)         // (C, 16*L0)
{
    const int c     = blockIdx.y;
    const int chunk = blockIdx.x;
    const int tid   = threadIdx.x;
    const int nthr  = blockDim.x;

    Taps T;
    T.he0 = h[4]; T.he1 = h[2]; T.he2 = h[0];
    T.ho0 = h[5]; T.ho1 = h[3]; T.ho2 = h[1];
    T.ge0 = g[4]; T.ge1 = g[2]; T.ge2 = g[0];
    T.go0 = g[5]; T.go1 = g[3]; T.go2 = g[1];

    // 14.4 KB total -> 8 blocks/CU (thread-capped)
    __shared__ __align__(16) float s1[520];
    __shared__ __align__(16) float s2[1032];
    __shared__ __align__(16) float s3[2056];

    const int L1 = 2*L0, L2 = 4*L0, L3 = 8*L0, L4 = 16*L0;

    const int lo4 = chunk * B_OUT;                        // multiple of 4
    const int hi4 = lo4 + B_OUT - 1;
    int lo3 = (lo4 >> 1) - 4; if (lo3 < 0) lo3 = 0;       // keep lo % 4 == 0
    int hi3 = (hi4 >> 1) + 1; if (hi3 > L3 - 1) hi3 = L3 - 1;
    int lo2 = (lo3 >> 1) - 2; if (lo2 < 0) lo2 = 0;
    int hi2 = (hi3 >> 1) + 1; if (hi2 > L2 - 1) hi2 = L2 - 1;
    int lo1 = (lo2 >> 1) - 2; if (lo1 < 0) lo1 = 0;
    int hi1 = (hi2 >> 1) + 1; if (hi1 > L1 - 1) hi1 = L1 - 1;

    const float* s0p = sig + (size_t)c * L0;
    const float* d3p = d3  + (size_t)c * L0;
    const float* d2p = d2  + (size_t)c * L1;
    const float* d1p = d1  + (size_t)c * L2;
    const float* d0p = d0  + (size_t)c * L3;
    float*       outp = out + (size_t)c * L4;

    synth_level<false>(s0p, 0, L0, d3p, s1, lo1, hi1, T, tid, nthr);
    __syncthreads();
    synth_level<false>(s1, lo1, L1, d2p, s2, lo2, hi2, T, tid, nthr);
    __syncthreads();
    synth_level<false>(s2, lo2, L2, d1p, s3, lo3, hi3, T, tid, nthr);
    __syncthreads();
    synth_level<true >(s3, lo3, L3, d0p, outp + lo4, lo4, hi4, T, tid, nthr);
}

extern "C" void kernel_launch(void* const* d_in, const int* in_sizes, int n_in,
                              void* d_out, int out_size, void* d_ws, size_t ws_size,
                              hipStream_t stream) {
    const float* sig = (const float*)d_in[0];
    const float* d0  = (const float*)d_in[1];
    const float* d1  = (const float*)d_in[2];
    const float* d2  = (const float*)d_in[3];
    const float* d3  = (const float*)d_in[4];
    const float* h   = (const float*)d_in[5];
    const float* g   = (const float*)d_in[6];
    float* out = (float*)d_out;

    dim3 grid(NCHUNK, C_CH);
    iwt_fused_kernel<<<grid, 256, 0, stream>>>(sig, d0, d1, d2, d3, h, g, out);
}